// Round 6
// baseline (502.215 us; speedup 1.0000x reference)
//
#include <hip/hip_runtime.h>
#include <hip/hip_bf16.h>

#define NNODES 10000
#define NEDGES 640000
#define NTOT   (NNODES + NEDGES)   // edges + self-loops
#define D_IN 128
#define H1 128
#define H2 64
#define EMB 64

#define NBUCKET 160        // buckets of 64 nodes: dst>>6 in [0,157)
#define BCAP    8192       // per-bucket capacity (avg 4160, max ~4450)
#define CHUNK   4096       // edges per bucket-pass block
#define NCHUNK  ((NTOT + CHUNK - 1) / CHUNK)   // 159
#define NTILE   ((NNODES + 31) / 32)           // 313
#define NBBLK   ((NNODES + 63) / 64)           // 157
#define GRID    256        // == #CUs: >=1 block/CU always fits -> co-resident
#define TB      256

struct Params {
    const float* x; const int* ei;
    const float* W1; const float* a_src1; const float* a_dst1; const float* b1;
    const float* W2; const float* a_src2; const float* a_dst2; const float* b2;
    const float* Wp; const float* bp;
    float* out;
    int* bar; int* bucket_cursor; int* bucket_arr; int* rowptr; int* csr_src;
    float* h1; float* as1; float* ad1; float* x1;
    float* h2; float* as2; float* ad2; float* x2;
};

// 40 KB union — phases reuse the same LDS.
union SMem {
    struct { int ordered[CHUNK]; int hist[NBUCKET]; int binStart[NBUCKET];
             int bincur[NBUCKET]; int gcur[NBUCKET]; int wtmp[4]; } p1;   // ~18.6 KB
    struct { int base[NBUCKET]; int wtmp[4]; int hist[64]; int bincur[64]; } p2;
    struct { float A[32 * 64]; float B[64 * 128]; } g;                    // 40 KB
};

// ---------------------------------------------------------------------------
// Hand-rolled grid barrier: counter slot k, all GRID blocks arrive then leave.
// Release-RMW flushes this block's prior writes to device scope; acquire-load
// invalidates local caches on leave (cross-XCD visibility).
// ---------------------------------------------------------------------------
__device__ __forceinline__ void gridbar(int* __restrict__ bar, int k) {
    __syncthreads();
    if (threadIdx.x == 0) {
        __hip_atomic_fetch_add(&bar[k], 1, __ATOMIC_RELEASE, __HIP_MEMORY_SCOPE_AGENT);
        while (__hip_atomic_load(&bar[k], __ATOMIC_ACQUIRE, __HIP_MEMORY_SCOPE_AGENT) < GRID)
            __builtin_amdgcn_s_sleep(2);
    }
    __syncthreads();
}

// ---------------------------------------------------------------------------
// CSR pass 1: one 4096-edge chunk -> bucketed (dst>>6) coalesced runs.
// Record pack: (dst<<16)|src  (both < 10000 < 2^14).
// ---------------------------------------------------------------------------
__device__ __forceinline__ void bucket_chunk(SMem& sm, int c, const int* __restrict__ ei,
                                             int* __restrict__ bucket_cursor,
                                             int* __restrict__ bucket_arr) {
    int tid = threadIdx.x;
    int base = c * CHUNK;
    int n = NTOT - base; if (n > CHUNK) n = CHUNK;

    int rec[CHUNK / 256];
#pragma unroll
    for (int k = 0; k < CHUNK / 256; ++k) {
        int i = base + k * 256 + tid;
        int r = 0;
        if (i < NTOT) {
            int s, d;
            if (i < NEDGES) { s = ei[i]; d = ei[NEDGES + i]; }
            else            { s = d = i - NEDGES; }
            r = (d << 16) | s;
        }
        rec[k] = r;
    }

    for (int b = tid; b < NBUCKET; b += 256) sm.p1.hist[b] = 0;
    __syncthreads();
#pragma unroll
    for (int k = 0; k < CHUNK / 256; ++k) {
        int i = base + k * 256 + tid;
        if (i < NTOT) atomicAdd(&sm.p1.hist[rec[k] >> 22], 1);
    }
    __syncthreads();

    {   // exclusive scan of 160 bins
        int v = (tid < NBUCKET) ? sm.p1.hist[tid] : 0;
        int lane = tid & 63, w = tid >> 6;
        int inc = v;
        for (int o = 1; o < 64; o <<= 1) {
            int t = __shfl_up(inc, o, 64);
            if (lane >= o) inc += t;
        }
        if (lane == 63) sm.p1.wtmp[w] = inc;
        __syncthreads();
        int pre = 0;
        for (int i = 0; i < w; ++i) pre += sm.p1.wtmp[i];
        if (tid < NBUCKET) {
            sm.p1.binStart[tid] = pre + inc - v;
            sm.p1.bincur[tid]   = pre + inc - v;
        }
    }
    __syncthreads();

#pragma unroll
    for (int k = 0; k < CHUNK / 256; ++k) {
        int i = base + k * 256 + tid;
        if (i < NTOT) {
            int pos = atomicAdd(&sm.p1.bincur[rec[k] >> 22], 1);
            sm.p1.ordered[pos] = rec[k];
        }
    }
    __syncthreads();

    for (int b = tid; b < NBUCKET; b += 256) {
        int cc = sm.p1.hist[b];
        sm.p1.gcur[b] = cc ? atomicAdd(&bucket_cursor[b], cc) : 0;
    }
    __syncthreads();

#pragma unroll
    for (int k = 0; k < CHUNK / 256; ++k) {
        int i = k * 256 + tid;
        if (i < n) {
            int r = sm.p1.ordered[i];
            int b = r >> 22;
            bucket_arr[b * BCAP + sm.p1.gcur[b] + (i - sm.p1.binStart[b])] = r;
        }
    }
}

// ---------------------------------------------------------------------------
// CSR pass 2: one bucket -> rowptr + csr_src. Each block redundantly scans
// the 160 bucket counts (cheap) to get its global base.
// ---------------------------------------------------------------------------
__device__ __forceinline__ void build_bucket(SMem& sm, int b,
                                             const int* __restrict__ bucket_cursor,
                                             const int* __restrict__ bucket_arr,
                                             int* __restrict__ rowptr,
                                             int* __restrict__ csr_src) {
    int tid = threadIdx.x;
    {   // scan bucket counts -> base[]
        int v = (tid < NBUCKET) ? bucket_cursor[tid] : 0;
        int lane = tid & 63, w = tid >> 6;
        int inc = v;
        for (int o = 1; o < 64; o <<= 1) {
            int t = __shfl_up(inc, o, 64);
            if (lane >= o) inc += t;
        }
        if (lane == 63) sm.p2.wtmp[w] = inc;
        __syncthreads();
        int pre = 0;
        for (int i = 0; i < w; ++i) pre += sm.p2.wtmp[i];
        if (tid < NBUCKET) sm.p2.base[tid] = pre + inc - v;
    }
    __syncthreads();
    int cnt = bucket_cursor[b];
    int base = sm.p2.base[b];
    const int* arr = bucket_arr + b * BCAP;

    if (tid < 64) sm.p2.hist[tid] = 0;
    __syncthreads();
    for (int i = tid; i < cnt; i += 256) atomicAdd(&sm.p2.hist[(arr[i] >> 16) & 63], 1);
    __syncthreads();

    if (tid < 64) {
        int v = sm.p2.hist[tid];
        int inc = v;
        for (int o = 1; o < 64; o <<= 1) {
            int t = __shfl_up(inc, o, 64);
            if (tid >= o) inc += t;
        }
        sm.p2.bincur[tid] = inc - v;
        int node = b * 64 + tid;
        if (node < NNODES) rowptr[node] = base + inc - v;
    }
    if (b == 0 && tid == 0) rowptr[NNODES] = NTOT;
    __syncthreads();

    for (int i = tid; i < cnt; i += 256) {
        int r = arr[i];
        int pos = base + atomicAdd(&sm.p2.bincur[(r >> 16) & 63], 1);
        csr_src[pos] = r & 0xFFFF;
    }
}

// ---------------------------------------------------------------------------
// One 32-row GEMM tile, chunked K (BK=64): C = A@B (+bias), optional fused
// dots (as = C·a_src, ad = C·a_dst) from the accumulator registers.
// ---------------------------------------------------------------------------
template <int K, int NC, bool BIAS, bool DOTS>
__device__ __forceinline__ void gemm_tile(SMem& sm, int t,
                                          const float* __restrict__ A,
                                          const float* __restrict__ B,
                                          const float* __restrict__ bias,
                                          float* __restrict__ C,
                                          const float* __restrict__ a_src,
                                          const float* __restrict__ a_dst,
                                          float* __restrict__ as,
                                          float* __restrict__ ad) {
    int tid = threadIdx.x;
    int row0 = t * 32;
    int tx = tid & 31;   // columns tx*CPT .. tx*CPT+CPT-1
    int ty = tid >> 5;   // rows ty + 8*rr
    constexpr int CPT = NC / 32;
    float acc[4][CPT];
#pragma unroll
    for (int rr = 0; rr < 4; ++rr)
#pragma unroll
        for (int cc = 0; cc < CPT; ++cc) acc[rr][cc] = 0.f;

    for (int kk = 0; kk < K; kk += 64) {
        float4* Al4 = (float4*)sm.g.A;
        const float4* A4 = (const float4*)(A + (size_t)row0 * K + kk);
        for (int idx = tid; idx < 32 * 16; idx += 256) {
            int r = idx >> 4, c = idx & 15;
            float4 z4 = {0.f, 0.f, 0.f, 0.f};
            Al4[idx] = (row0 + r < NNODES) ? A4[r * (K / 4) + c] : z4;
        }
        float4* Bl4 = (float4*)sm.g.B;
        const float4* B4 = (const float4*)(B + (size_t)kk * NC);
        for (int idx = tid; idx < 64 * NC / 4; idx += 256) Bl4[idx] = B4[idx];
        __syncthreads();

        for (int k = 0; k < 64; ++k) {
            float bv[CPT];
            const float* Bk = &sm.g.B[k * NC + tx * CPT];
#pragma unroll
            for (int cc = 0; cc < CPT; ++cc) bv[cc] = Bk[cc];
#pragma unroll
            for (int rr = 0; rr < 4; ++rr) {
                float a = sm.g.A[(ty + 8 * rr) * 64 + k];
#pragma unroll
                for (int cc = 0; cc < CPT; ++cc) acc[rr][cc] = fmaf(a, bv[cc], acc[rr][cc]);
            }
        }
        __syncthreads();
    }

#pragma unroll
    for (int rr = 0; rr < 4; ++rr) {
        int gr = row0 + ty + 8 * rr;
        if (gr < NNODES) {
#pragma unroll
            for (int cc = 0; cc < CPT; ++cc) {
                int c = tx * CPT + cc;
                float v = acc[rr][cc];
                if (BIAS) v += bias[c];
                C[(size_t)gr * NC + c] = v;
            }
        }
    }

    if (DOTS) {
        float asv[CPT], adv[CPT];
#pragma unroll
        for (int cc = 0; cc < CPT; ++cc) {
            asv[cc] = a_src[tx * CPT + cc];
            adv[cc] = a_dst[tx * CPT + cc];
        }
#pragma unroll
        for (int rr = 0; rr < 4; ++rr) {
            float s1 = 0.f, s2 = 0.f;
#pragma unroll
            for (int cc = 0; cc < CPT; ++cc) {
                s1 = fmaf(acc[rr][cc], asv[cc], s1);
                s2 = fmaf(acc[rr][cc], adv[cc], s2);
            }
#pragma unroll
            for (int o = 1; o < 32; o <<= 1) {
                s1 += __shfl_xor(s1, o, 64);
                s2 += __shfl_xor(s2, o, 64);
            }
            int gr = row0 + ty + 8 * rr;
            if (tx == 0 && gr < NNODES) { as[gr] = s1; ad[gr] = s2; }
        }
    }
}

// ---------------------------------------------------------------------------
// Fused edge-softmax + weighted aggregation, one wave per node (grid-stride).
// Softmax without max-shift (shift-invariant; logits are O(1)).
// ---------------------------------------------------------------------------
template <int H>
__device__ __forceinline__ void agg_nodes(const int* __restrict__ rowptr,
                                          const int* __restrict__ csr_src,
                                          const float* __restrict__ h,
                                          const float* __restrict__ as,
                                          const float* __restrict__ ad,
                                          const float* __restrict__ bias,
                                          float* __restrict__ out) {
    int gw = (blockIdx.x * blockDim.x + threadIdx.x) >> 6;
    int nw = (GRID * TB) >> 6;
    int lane = threadIdx.x & 63;
    const float2* h2 = (const float2*)h;

    for (int wid = gw; wid < NNODES; wid += nw) {
        int beg = rowptr[wid];
        int end = rowptr[wid + 1];
        float ad_d = ad[wid];
        float z = 0.f, acc0 = 0.f, acc1 = 0.f;

        for (int chunk = beg; chunk < end; chunk += 64) {
            int myj = chunk + lane;
            int cnt = end - chunk; if (cnt > 64) cnt = 64;
            int s_l = 0;
            float e_l = 0.f;
            if (myj < end) {
                s_l = csr_src[myj];
                float l = as[s_l] + ad_d;
                l = (l > 0.f) ? l : 0.2f * l;
                e_l = __expf(l);
            }
            z += e_l;
            int cnt4 = (cnt + 3) & ~3;   // padded lanes carry e=0, s=0 -> harmless
            for (int t = 0; t < cnt4; t += 4) {
#pragma unroll
                for (int u = 0; u < 4; ++u) {
                    int tt = __builtin_amdgcn_readfirstlane(t + u);
                    int s = __builtin_amdgcn_readlane(s_l, tt);
                    float e = __int_as_float(
                        __builtin_amdgcn_readlane(__float_as_int(e_l), tt));
                    if (H == 128) {
                        float2 v = h2[(size_t)s * 64 + lane];
                        acc0 = fmaf(e, v.x, acc0);
                        acc1 = fmaf(e, v.y, acc1);
                    } else {
                        float v = h[(size_t)s * H + lane];
                        acc0 = fmaf(e, v, acc0);
                    }
                }
            }
        }
        for (int o = 32; o; o >>= 1) z += __shfl_xor(z, o, 64);
        float rz = 1.f / z;
        if (H == 128) {
            float2 bb = ((const float2*)bias)[lane];
            float2 o2;
            o2.x = fmaxf(acc0 * rz + bb.x, 0.f);
            o2.y = fmaxf(acc1 * rz + bb.y, 0.f);
            ((float2*)out)[(size_t)wid * 64 + lane] = o2;
        } else {
            float o0 = fmaxf(acc0 * rz + bias[lane], 0.f);
            out[(size_t)wid * H + lane] = o0;
        }
    }
}

// ---------------------------------------------------------------------------
// Mega-kernel, regular launch + hand-rolled grid barriers.
// Phase 1 overlaps CSR bucketing (blocks 0..158) with GEMM1 (blocks 159..255).
// ---------------------------------------------------------------------------
__global__ __launch_bounds__(TB) void mega(Params p) {
    __shared__ SMem sm;
    int bid = blockIdx.x;

    // phase 1: CSR bucket pass || GEMM1 + dots (independent work)
    if (bid < NCHUNK) {
        bucket_chunk(sm, bid, p.ei, p.bucket_cursor, p.bucket_arr);
    } else {
        for (int t = bid - NCHUNK; t < NTILE; t += GRID - NCHUNK)
            gemm_tile<D_IN, H1, false, true>(sm, t, p.x, p.W1, nullptr, p.h1,
                                             p.a_src1, p.a_dst1, p.as1, p.ad1);
    }
    gridbar(p.bar, 0);

    // phase 2: build rowptr + csr_src
    if (bid < NBBLK)
        build_bucket(sm, bid, p.bucket_cursor, p.bucket_arr, p.rowptr, p.csr_src);
    gridbar(p.bar, 1);

    // phase 3: layer-1 softmax-aggregate
    agg_nodes<H1>(p.rowptr, p.csr_src, p.h1, p.as1, p.ad1, p.b1, p.x1);
    gridbar(p.bar, 2);

    // phase 4: GEMM2 + dots
    for (int t = bid; t < NTILE; t += GRID)
        gemm_tile<H1, H2, false, true>(sm, t, p.x1, p.W2, nullptr, p.h2,
                                       p.a_src2, p.a_dst2, p.as2, p.ad2);
    gridbar(p.bar, 3);

    // phase 5: layer-2 softmax-aggregate
    agg_nodes<H2>(p.rowptr, p.csr_src, p.h2, p.as2, p.ad2, p.b2, p.x2);
    gridbar(p.bar, 4);

    // phase 6: projection
    for (int t = bid; t < NTILE; t += GRID)
        gemm_tile<H2, EMB, true, false>(sm, t, p.x2, p.Wp, p.bp, p.out,
                                        nullptr, nullptr, nullptr, nullptr);
}

// ---------------------------------------------------------------------------

extern "C" void kernel_launch(void* const* d_in, const int* in_sizes, int n_in,
                              void* d_out, int out_size, void* d_ws, size_t ws_size,
                              hipStream_t stream) {
    char* ws = (char*)d_ws;
    size_t off = 0;
    auto alloc = [&](size_t bytes) {
        void* p = ws + off;
        off = (off + bytes + 255) & ~(size_t)255;
        return p;
    };

    Params p;
    p.x      = (const float*)d_in[0];
    p.ei     = (const int*)d_in[1];
    p.W1     = (const float*)d_in[2];
    p.a_src1 = (const float*)d_in[3];
    p.a_dst1 = (const float*)d_in[4];
    p.b1     = (const float*)d_in[5];
    p.W2     = (const float*)d_in[6];
    p.a_src2 = (const float*)d_in[7];
    p.a_dst2 = (const float*)d_in[8];
    p.b2     = (const float*)d_in[9];
    p.Wp     = (const float*)d_in[10];
    p.bp     = (const float*)d_in[11];
    p.out    = (float*)d_out;

    // bar + bucket_cursor first: one small memset zeroes both
    p.bar           = (int*)alloc(16 * 4);
    p.bucket_cursor = (int*)alloc(NBUCKET * 4);
    size_t zero_bytes = off;   // 256 + 768 = 1024
    p.bucket_arr    = (int*)alloc((size_t)NBUCKET * BCAP * 4);   // 5.2 MB
    p.rowptr        = (int*)alloc((NNODES + 1) * 4);
    p.csr_src       = (int*)alloc((size_t)NTOT * 4);
    p.h1            = (float*)alloc((size_t)NNODES * H1 * 4);
    p.as1           = (float*)alloc(NNODES * 4);
    p.ad1           = (float*)alloc(NNODES * 4);
    p.x1            = (float*)alloc((size_t)NNODES * H1 * 4);
    p.h2            = (float*)alloc((size_t)NNODES * H2 * 4);
    p.as2           = (float*)alloc(NNODES * 4);
    p.ad2           = (float*)alloc(NNODES * 4);
    p.x2            = (float*)alloc((size_t)NNODES * H2 * 4);
    (void)ws_size; (void)in_sizes; (void)n_in; (void)out_size;

    hipMemsetAsync(d_ws, 0, zero_bytes, stream);
    mega<<<GRID, TB, 0, stream>>>(p);
}

// Round 7
// 182.894 us; speedup vs baseline: 2.7459x; 2.7459x over previous
//
#include <hip/hip_runtime.h>
#include <hip/hip_bf16.h>

#define NNODES 10000
#define NEDGES 640000
#define NTOT   (NNODES + NEDGES)   // edges + self-loops
#define D_IN 128
#define H1 128
#define H2 64
#define EMB 64

#define NBUCKET 160        // buckets of 64 nodes: dst>>6 in [0,157)
#define BCAP    8192       // per-bucket capacity (avg 4160, max ~4450)
#define CHUNK   4096       // edges per pass-1 block

// ---------------------------------------------------------------------------
// Pass 1: bucket edges by dst>>6 into per-bucket arrays, coalesced writes.
// Record pack: (dst<<16)|src  (both < 10000 < 2^14).
// ---------------------------------------------------------------------------

__global__ __launch_bounds__(256) void bucket_kernel(const int* __restrict__ ei,
                                                     int* __restrict__ bucket_cursor,
                                                     int* __restrict__ bucket_arr) {
    __shared__ int ordered[CHUNK];
    __shared__ int hist[NBUCKET];
    __shared__ int binStart[NBUCKET];
    __shared__ int bincur[NBUCKET];
    __shared__ int gcur[NBUCKET];
    __shared__ int wtmp[4];

    int tid = threadIdx.x;
    int base = blockIdx.x * CHUNK;
    int n = NTOT - base; if (n > CHUNK) n = CHUNK;

    int rec[CHUNK / 256];
#pragma unroll
    for (int k = 0; k < CHUNK / 256; ++k) {
        int i = base + k * 256 + tid;
        int r = 0;
        if (i < NTOT) {
            int s, d;
            if (i < NEDGES) { s = ei[i]; d = ei[NEDGES + i]; }
            else            { s = d = i - NEDGES; }
            r = (d << 16) | s;
        }
        rec[k] = r;
    }

    for (int b = tid; b < NBUCKET; b += 256) hist[b] = 0;
    __syncthreads();
#pragma unroll
    for (int k = 0; k < CHUNK / 256; ++k) {
        int i = base + k * 256 + tid;
        if (i < NTOT) atomicAdd(&hist[rec[k] >> 22], 1);
    }
    __syncthreads();

    {   // exclusive scan of 160 bins across the block
        int v = (tid < NBUCKET) ? hist[tid] : 0;
        int lane = tid & 63, w = tid >> 6;
        int inc = v;
        for (int o = 1; o < 64; o <<= 1) {
            int t = __shfl_up(inc, o, 64);
            if (lane >= o) inc += t;
        }
        if (lane == 63) wtmp[w] = inc;
        __syncthreads();
        int pre = 0;
        for (int i = 0; i < w; ++i) pre += wtmp[i];
        if (tid < NBUCKET) {
            binStart[tid] = pre + inc - v;
            bincur[tid]   = pre + inc - v;
        }
    }
    __syncthreads();

#pragma unroll
    for (int k = 0; k < CHUNK / 256; ++k) {
        int i = base + k * 256 + tid;
        if (i < NTOT) {
            int pos = atomicAdd(&bincur[rec[k] >> 22], 1);
            ordered[pos] = rec[k];
        }
    }
    __syncthreads();

    for (int b = tid; b < NBUCKET; b += 256) {
        int c = hist[b];
        gcur[b] = c ? atomicAdd(&bucket_cursor[b], c) : 0;
    }
    __syncthreads();

#pragma unroll
    for (int k = 0; k < CHUNK / 256; ++k) {
        int i = k * 256 + tid;
        if (i < n) {
            int r = ordered[i];
            int b = r >> 22;
            bucket_arr[b * BCAP + gcur[b] + (i - binStart[b])] = r;
        }
    }
}

// ---------------------------------------------------------------------------
// Pass 2: one block per bucket -> rowptr + csr_src. Each block redundantly
// scans the 160 bucket counts (cheap) to get its global base — no separate
// scan dispatch.
// ---------------------------------------------------------------------------

__global__ __launch_bounds__(256) void build_kernel(const int* __restrict__ bucket_cursor,
                                                    const int* __restrict__ bucket_arr,
                                                    int* __restrict__ rowptr,
                                                    int* __restrict__ csr_src) {
    __shared__ int sbase[NBUCKET];
    __shared__ int wtmp[4];
    __shared__ int hist[64];
    __shared__ int bincur[64];
    int tid = threadIdx.x;
    int b = blockIdx.x;

    {   // scan the 160 bucket counts -> sbase[]
        int v = (tid < NBUCKET) ? bucket_cursor[tid] : 0;
        int lane = tid & 63, w = tid >> 6;
        int inc = v;
        for (int o = 1; o < 64; o <<= 1) {
            int t = __shfl_up(inc, o, 64);
            if (lane >= o) inc += t;
        }
        if (lane == 63) wtmp[w] = inc;
        __syncthreads();
        int pre = 0;
        for (int i = 0; i < w; ++i) pre += wtmp[i];
        if (tid < NBUCKET) sbase[tid] = pre + inc - v;
    }
    __syncthreads();

    int cnt = bucket_cursor[b];
    int base = sbase[b];
    const int* arr = bucket_arr + b * BCAP;

    if (tid < 64) hist[tid] = 0;
    __syncthreads();
    for (int i = tid; i < cnt; i += 256) atomicAdd(&hist[(arr[i] >> 16) & 63], 1);
    __syncthreads();

    if (tid < 64) {   // wave 0: exclusive scan of 64 bins
        int v = hist[tid];
        int inc = v;
        for (int o = 1; o < 64; o <<= 1) {
            int t = __shfl_up(inc, o, 64);
            if (tid >= o) inc += t;
        }
        bincur[tid] = inc - v;
        int node = b * 64 + tid;
        if (node < NNODES) rowptr[node] = base + inc - v;
    }
    if (b == 0 && tid == 0) rowptr[NNODES] = NTOT;
    __syncthreads();

    for (int i = tid; i < cnt; i += 256) {
        int r = arr[i];
        int pos = base + atomicAdd(&bincur[(r >> 16) & 63], 1);
        csr_src[pos] = r & 0xFFFF;
    }
}

// ---------------------------------------------------------------------------
// Small fp32 GEMM: C[M x NC] = A[M x K] @ B[K x NC] (+ bias).  32 rows/block.
// DOTS: also emit as[i]=C[i]·a_src, ad[i]=C[i]·a_dst from registers.
// ---------------------------------------------------------------------------

template <int K, int NC, bool BIAS, bool DOTS>
__global__ __launch_bounds__(256) void gemm_kernel(const float* __restrict__ A,
                                                   const float* __restrict__ B,
                                                   const float* __restrict__ bias,
                                                   float* __restrict__ C, int M,
                                                   const float* __restrict__ a_src,
                                                   const float* __restrict__ a_dst,
                                                   float* __restrict__ as,
                                                   float* __restrict__ ad) {
    __shared__ float Alds[32 * K];
    __shared__ float Blds[K * NC];
    int tid = threadIdx.x;
    int row0 = blockIdx.x * 32;

    const float4* A4 = (const float4*)(A + (size_t)row0 * K);
    float4* Al4 = (float4*)Alds;
    constexpr int A4N = 32 * K / 4;
    for (int idx = tid; idx < A4N; idx += 256) {
        int r = idx / (K / 4);
        float4 z4 = {0.f, 0.f, 0.f, 0.f};
        Al4[idx] = (row0 + r < M) ? A4[idx] : z4;
    }
    const float4* B4 = (const float4*)B;
    float4* Bl4 = (float4*)Blds;
    constexpr int B4N = K * NC / 4;
    for (int idx = tid; idx < B4N; idx += 256) Bl4[idx] = B4[idx];
    __syncthreads();

    int tx = tid & 31;   // columns tx*CPT .. tx*CPT+CPT-1 (contiguous)
    int ty = tid >> 5;   // rows ty + 8*rr
    constexpr int CPT = NC / 32;
    float acc[4][CPT];
#pragma unroll
    for (int rr = 0; rr < 4; ++rr)
#pragma unroll
        for (int cc = 0; cc < CPT; ++cc) acc[rr][cc] = 0.f;

    for (int k = 0; k < K; ++k) {
        float bv[CPT];
        const float* Bk = &Blds[k * NC + tx * CPT];
#pragma unroll
        for (int cc = 0; cc < CPT; ++cc) bv[cc] = Bk[cc];
#pragma unroll
        for (int rr = 0; rr < 4; ++rr) {
            float a = Alds[(ty + 8 * rr) * K + k];
#pragma unroll
            for (int cc = 0; cc < CPT; ++cc) acc[rr][cc] = fmaf(a, bv[cc], acc[rr][cc]);
        }
    }

#pragma unroll
    for (int rr = 0; rr < 4; ++rr) {
        int gr = row0 + ty + 8 * rr;
        if (gr < M) {
#pragma unroll
            for (int cc = 0; cc < CPT; ++cc) {
                int c = tx * CPT + cc;
                float v = acc[rr][cc];
                if (BIAS) v += bias[c];
                C[(size_t)gr * NC + c] = v;
            }
        }
    }

    if (DOTS) {
        float asv[CPT], adv[CPT];
#pragma unroll
        for (int cc = 0; cc < CPT; ++cc) {
            asv[cc] = a_src[tx * CPT + cc];
            adv[cc] = a_dst[tx * CPT + cc];
        }
#pragma unroll
        for (int rr = 0; rr < 4; ++rr) {
            float s1 = 0.f, s2 = 0.f;
#pragma unroll
            for (int cc = 0; cc < CPT; ++cc) {
                s1 = fmaf(acc[rr][cc], asv[cc], s1);
                s2 = fmaf(acc[rr][cc], adv[cc], s2);
            }
#pragma unroll
            for (int o = 1; o < 32; o <<= 1) {
                s1 += __shfl_xor(s1, o, 64);
                s2 += __shfl_xor(s2, o, 64);
            }
            int gr = row0 + ty + 8 * rr;
            if (tx == 0 && gr < M) { as[gr] = s1; ad[gr] = s2; }
        }
    }
}

// ---------------------------------------------------------------------------
// Fused edge-softmax + weighted aggregation, one wave per destination node.
// Softmax without max-shift (shift-invariant; logits are O(1)).
// Gather loop unrolled x8 for more outstanding L2 reads per wave.
// ---------------------------------------------------------------------------

template <int H>
__global__ __launch_bounds__(256) void agg_kernel(const int* __restrict__ rowptr,
                                                  const int* __restrict__ csr_src,
                                                  const float* __restrict__ h,
                                                  const float* __restrict__ as,
                                                  const float* __restrict__ ad,
                                                  const float* __restrict__ bias,
                                                  float* __restrict__ out) {
    int wid = (blockIdx.x * blockDim.x + threadIdx.x) >> 6;
    int lane = threadIdx.x & 63;
    if (wid >= NNODES) return;
    int beg = rowptr[wid];
    int end = rowptr[wid + 1];
    float ad_d = ad[wid];

    const float2* h2 = (const float2*)h;
    float z = 0.f, acc0 = 0.f, acc1 = 0.f;

    for (int chunk = beg; chunk < end; chunk += 64) {
        int myj = chunk + lane;
        int cnt = end - chunk; if (cnt > 64) cnt = 64;
        int s_l = 0;
        float e_l = 0.f;
        if (myj < end) {
            s_l = csr_src[myj];
            float l = as[s_l] + ad_d;
            l = (l > 0.f) ? l : 0.2f * l;
            e_l = __expf(l);
        }
        z += e_l;
        int cnt8 = (cnt + 7) & ~7;   // padded lanes carry e=0, s=0 -> harmless
        for (int t = 0; t < cnt8; t += 8) {
#pragma unroll
            for (int u = 0; u < 8; ++u) {
                int tt = __builtin_amdgcn_readfirstlane(t + u);
                int s = __builtin_amdgcn_readlane(s_l, tt);
                float e = __int_as_float(
                    __builtin_amdgcn_readlane(__float_as_int(e_l), tt));
                if (H == 128) {
                    float2 v = h2[(size_t)s * 64 + lane];
                    acc0 = fmaf(e, v.x, acc0);
                    acc1 = fmaf(e, v.y, acc1);
                } else {
                    float v = h[(size_t)s * H + lane];
                    acc0 = fmaf(e, v, acc0);
                }
            }
        }
    }
    for (int o = 32; o; o >>= 1) z += __shfl_xor(z, o, 64);
    float rz = 1.f / z;
    if (H == 128) {
        float2 bb = ((const float2*)bias)[lane];
        float2 o2;
        o2.x = fmaxf(acc0 * rz + bb.x, 0.f);
        o2.y = fmaxf(acc1 * rz + bb.y, 0.f);
        ((float2*)out)[(size_t)wid * 64 + lane] = o2;
    } else {
        float o0 = fmaxf(acc0 * rz + bias[lane], 0.f);
        out[(size_t)wid * H + lane] = o0;
    }
}

// ---------------------------------------------------------------------------

extern "C" void kernel_launch(void* const* d_in, const int* in_sizes, int n_in,
                              void* d_out, int out_size, void* d_ws, size_t ws_size,
                              hipStream_t stream) {
    const float* x      = (const float*)d_in[0];
    const int*   ei     = (const int*)d_in[1];
    const float* W1     = (const float*)d_in[2];
    const float* a_src1 = (const float*)d_in[3];
    const float* a_dst1 = (const float*)d_in[4];
    const float* b1     = (const float*)d_in[5];
    const float* W2     = (const float*)d_in[6];
    const float* a_src2 = (const float*)d_in[7];
    const float* a_dst2 = (const float*)d_in[8];
    const float* b2     = (const float*)d_in[9];
    const float* Wp     = (const float*)d_in[10];
    const float* bp     = (const float*)d_in[11];
    float* out = (float*)d_out;

    char* ws = (char*)d_ws;
    size_t off = 0;
    auto alloc = [&](size_t bytes) {
        void* p = ws + off;
        off = (off + bytes + 255) & ~(size_t)255;
        return p;
    };
    int*   bucket_cursor = (int*)alloc(NBUCKET * 4);
    int*   bucket_arr    = (int*)alloc((size_t)NBUCKET * BCAP * 4);   // 5.2 MB
    int*   rowptr  = (int*)alloc((NNODES + 1) * 4);
    int*   csr_src = (int*)alloc((size_t)NTOT * 4);
    float* h1      = (float*)alloc((size_t)NNODES * H1 * 4);
    float* as1     = (float*)alloc(NNODES * 4);
    float* ad1     = (float*)alloc(NNODES * 4);
    float* x1      = (float*)alloc((size_t)NNODES * H1 * 4);
    float* h2      = (float*)alloc((size_t)NNODES * H2 * 4);
    float* as2     = (float*)alloc(NNODES * 4);
    float* ad2     = (float*)alloc(NNODES * 4);
    float* x2      = (float*)alloc((size_t)NNODES * H2 * 4);
    (void)ws_size;

    const int TB = 256;
    int gemm_b = (NNODES + 31) / 32;            // 313
    int wave_b = (NNODES * 64 + TB - 1) / TB;   // 2500 (one wave per node)
    int p1_b = (NTOT + CHUNK - 1) / CHUNK;      // 159

    // CSR build (bucketed counting sort)
    hipMemsetAsync(bucket_cursor, 0, NBUCKET * 4, stream);
    bucket_kernel<<<p1_b, TB, 0, stream>>>(ei, bucket_cursor, bucket_arr);
    build_kernel<<<(NNODES + 63) / 64, TB, 0, stream>>>(bucket_cursor,
                                                        bucket_arr, rowptr, csr_src);

    // layer 1 (dots fused into GEMM epilogue)
    gemm_kernel<D_IN, H1, false, true><<<gemm_b, TB, 0, stream>>>(
        x, W1, nullptr, h1, NNODES, a_src1, a_dst1, as1, ad1);
    agg_kernel<H1><<<wave_b, TB, 0, stream>>>(rowptr, csr_src, h1, as1, ad1, b1, x1);

    // layer 2
    gemm_kernel<H1, H2, false, true><<<gemm_b, TB, 0, stream>>>(
        x1, W2, nullptr, h2, NNODES, a_src2, a_dst2, as2, ad2);
    agg_kernel<H2><<<wave_b, TB, 0, stream>>>(rowptr, csr_src, h2, as2, ad2, b2, x2);

    // projection -> output
    gemm_kernel<H2, EMB, true, false><<<gemm_b, TB, 0, stream>>>(
        x2, Wp, bp, out, NNODES, nullptr, nullptr, nullptr, nullptr);
}

// Round 8
// 162.867 us; speedup vs baseline: 3.0836x; 1.1230x over previous
//
#include <hip/hip_runtime.h>
#include <hip/hip_bf16.h>

#define NNODES 10000
#define NEDGES 640000
#define NTOT   (NNODES + NEDGES)   // edges + self-loops
#define D_IN 128
#define H1 128
#define H2 64
#define EMB 64

#define NBUCKET 160        // buckets of 64 nodes: dst>>6 in [0,157)
#define BCAP    8192       // per-bucket capacity (avg 4160, max ~4450)
#define CHUNK   4096       // edges per bucket-pass block
#define NCHUNK  ((NTOT + CHUNK - 1) / CHUNK)   // 159
#define NTILE   ((NNODES + 31) / 32)           // 313

typedef _Float16 half2v __attribute__((ext_vector_type(2)));
typedef _Float16 half4v __attribute__((ext_vector_type(4)));

// 40 KB union: bucket pass (~18.6 KB) / gemm1 BK=64 tiles (8 + 32 KB)
union SMemA {
    struct { int ordered[CHUNK]; int hist[NBUCKET]; int binStart[NBUCKET];
             int bincur[NBUCKET]; int gcur[NBUCKET]; int wtmp[4]; } p1;
    struct { float A[32 * 64]; float B[64 * 128]; } g;
};

// ---------------------------------------------------------------------------
// CSR pass 1 (device fn): one 4096-edge chunk -> bucketed (dst>>6) runs.
// Record pack: (dst<<16)|src.
// ---------------------------------------------------------------------------
__device__ __forceinline__ void bucket_chunk(SMemA& sm, int c, const int* __restrict__ ei,
                                             int* __restrict__ bucket_cursor,
                                             int* __restrict__ bucket_arr) {
    int tid = threadIdx.x;
    int base = c * CHUNK;
    int n = NTOT - base; if (n > CHUNK) n = CHUNK;

    int rec[CHUNK / 256];
#pragma unroll
    for (int k = 0; k < CHUNK / 256; ++k) {
        int i = base + k * 256 + tid;
        int r = 0;
        if (i < NTOT) {
            int s, d;
            if (i < NEDGES) { s = ei[i]; d = ei[NEDGES + i]; }
            else            { s = d = i - NEDGES; }
            r = (d << 16) | s;
        }
        rec[k] = r;
    }

    for (int b = tid; b < NBUCKET; b += 256) sm.p1.hist[b] = 0;
    __syncthreads();
#pragma unroll
    for (int k = 0; k < CHUNK / 256; ++k) {
        int i = base + k * 256 + tid;
        if (i < NTOT) atomicAdd(&sm.p1.hist[rec[k] >> 22], 1);
    }
    __syncthreads();

    {   // exclusive scan of 160 bins
        int v = (tid < NBUCKET) ? sm.p1.hist[tid] : 0;
        int lane = tid & 63, w = tid >> 6;
        int inc = v;
        for (int o = 1; o < 64; o <<= 1) {
            int t = __shfl_up(inc, o, 64);
            if (lane >= o) inc += t;
        }
        if (lane == 63) sm.p1.wtmp[w] = inc;
        __syncthreads();
        int pre = 0;
        for (int i = 0; i < w; ++i) pre += sm.p1.wtmp[i];
        if (tid < NBUCKET) {
            sm.p1.binStart[tid] = pre + inc - v;
            sm.p1.bincur[tid]   = pre + inc - v;
        }
    }
    __syncthreads();

#pragma unroll
    for (int k = 0; k < CHUNK / 256; ++k) {
        int i = base + k * 256 + tid;
        if (i < NTOT) {
            int pos = atomicAdd(&sm.p1.bincur[rec[k] >> 22], 1);
            sm.p1.ordered[pos] = rec[k];
        }
    }
    __syncthreads();

    for (int b = tid; b < NBUCKET; b += 256) {
        int cc = sm.p1.hist[b];
        sm.p1.gcur[b] = cc ? atomicAdd(&bucket_cursor[b], cc) : 0;
    }
    __syncthreads();

#pragma unroll
    for (int k = 0; k < CHUNK / 256; ++k) {
        int i = k * 256 + tid;
        if (i < n) {
            int r = sm.p1.ordered[i];
            int b = r >> 22;
            bucket_arr[b * BCAP + sm.p1.gcur[b] + (i - sm.p1.binStart[b])] = r;
        }
    }
}

// ---------------------------------------------------------------------------
// GEMM1 tile (device fn): 32 rows, K=128 chunked at BK=64. Emits h1 as fp16
// (gather table) + as1/ad1 dots from fp32 accumulators.
// ---------------------------------------------------------------------------
__device__ __forceinline__ void gemm1_tile(SMemA& sm, int t,
                                           const float* __restrict__ x,
                                           const float* __restrict__ W1,
                                           const float* __restrict__ a_src1,
                                           const float* __restrict__ a_dst1,
                                           _Float16* __restrict__ h1h,
                                           float* __restrict__ as1,
                                           float* __restrict__ ad1) {
    int tid = threadIdx.x;
    int row0 = t * 32;
    int tx = tid & 31;   // columns tx*4 .. tx*4+3
    int ty = tid >> 5;   // rows ty + 8*rr
    float acc[4][4];
#pragma unroll
    for (int rr = 0; rr < 4; ++rr)
#pragma unroll
        for (int cc = 0; cc < 4; ++cc) acc[rr][cc] = 0.f;

    for (int kk = 0; kk < D_IN; kk += 64) {
        float4* Al4 = (float4*)sm.g.A;
        for (int idx = tid; idx < 32 * 16; idx += 256) {
            int r = idx >> 4, c = idx & 15;
            float4 z4 = {0.f, 0.f, 0.f, 0.f};
            Al4[idx] = (row0 + r < NNODES)
                ? ((const float4*)(x + (size_t)(row0 + r) * D_IN + kk))[c] : z4;
        }
        float4* Bl4 = (float4*)sm.g.B;
        const float4* B4 = (const float4*)(W1 + (size_t)kk * H1);
        for (int idx = tid; idx < 64 * H1 / 4; idx += 256) Bl4[idx] = B4[idx];
        __syncthreads();

        for (int k = 0; k < 64; ++k) {
            float bv[4];
            const float* Bk = &sm.g.B[k * H1 + tx * 4];
#pragma unroll
            for (int cc = 0; cc < 4; ++cc) bv[cc] = Bk[cc];
#pragma unroll
            for (int rr = 0; rr < 4; ++rr) {
                float a = sm.g.A[(ty + 8 * rr) * 64 + k];
#pragma unroll
                for (int cc = 0; cc < 4; ++cc) acc[rr][cc] = fmaf(a, bv[cc], acc[rr][cc]);
            }
        }
        __syncthreads();
    }

#pragma unroll
    for (int rr = 0; rr < 4; ++rr) {
        int gr = row0 + ty + 8 * rr;
        if (gr < NNODES) {
            half4v hv;
            hv.x = (_Float16)acc[rr][0]; hv.y = (_Float16)acc[rr][1];
            hv.z = (_Float16)acc[rr][2]; hv.w = (_Float16)acc[rr][3];
            ((half4v*)(h1h + (size_t)gr * H1))[tx] = hv;
        }
    }

    float asv[4], adv[4];
#pragma unroll
    for (int cc = 0; cc < 4; ++cc) {
        asv[cc] = a_src1[tx * 4 + cc];
        adv[cc] = a_dst1[tx * 4 + cc];
    }
#pragma unroll
    for (int rr = 0; rr < 4; ++rr) {
        float s1 = 0.f, s2 = 0.f;
#pragma unroll
        for (int cc = 0; cc < 4; ++cc) {
            s1 = fmaf(acc[rr][cc], asv[cc], s1);
            s2 = fmaf(acc[rr][cc], adv[cc], s2);
        }
#pragma unroll
        for (int o = 1; o < 32; o <<= 1) {
            s1 += __shfl_xor(s1, o, 64);
            s2 += __shfl_xor(s2, o, 64);
        }
        int gr = row0 + ty + 8 * rr;
        if (tx == 0 && gr < NNODES) { as1[gr] = s1; ad1[gr] = s2; }
    }
}

// ---------------------------------------------------------------------------
// Kernel A: blocks [0,NCHUNK) bucket the edges; blocks [NCHUNK,NCHUNK+NTILE)
// run GEMM1. Independent work, one dispatch.
// ---------------------------------------------------------------------------
__global__ __launch_bounds__(256) void csr_gemm1_kernel(const int* __restrict__ ei,
                                                        int* __restrict__ bucket_cursor,
                                                        int* __restrict__ bucket_arr,
                                                        const float* __restrict__ x,
                                                        const float* __restrict__ W1,
                                                        const float* __restrict__ a_src1,
                                                        const float* __restrict__ a_dst1,
                                                        _Float16* __restrict__ h1h,
                                                        float* __restrict__ as1,
                                                        float* __restrict__ ad1) {
    __shared__ SMemA sm;
    int bid = blockIdx.x;
    if (bid < NCHUNK)
        bucket_chunk(sm, bid, ei, bucket_cursor, bucket_arr);
    else
        gemm1_tile(sm, bid - NCHUNK, x, W1, a_src1, a_dst1, h1h, as1, ad1);
}

// ---------------------------------------------------------------------------
// Kernel B: one block per bucket -> rowptr + csr_src (redundant 160-scan).
// ---------------------------------------------------------------------------
__global__ __launch_bounds__(256) void build_kernel(const int* __restrict__ bucket_cursor,
                                                    const int* __restrict__ bucket_arr,
                                                    int* __restrict__ rowptr,
                                                    int* __restrict__ csr_src) {
    __shared__ int sbase[NBUCKET];
    __shared__ int wtmp[4];
    __shared__ int hist[64];
    __shared__ int bincur[64];
    int tid = threadIdx.x;
    int b = blockIdx.x;

    {   // scan the 160 bucket counts -> sbase[]
        int v = (tid < NBUCKET) ? bucket_cursor[tid] : 0;
        int lane = tid & 63, w = tid >> 6;
        int inc = v;
        for (int o = 1; o < 64; o <<= 1) {
            int t = __shfl_up(inc, o, 64);
            if (lane >= o) inc += t;
        }
        if (lane == 63) wtmp[w] = inc;
        __syncthreads();
        int pre = 0;
        for (int i = 0; i < w; ++i) pre += wtmp[i];
        if (tid < NBUCKET) sbase[tid] = pre + inc - v;
    }
    __syncthreads();

    int cnt = bucket_cursor[b];
    int base = sbase[b];
    const int* arr = bucket_arr + b * BCAP;

    if (tid < 64) hist[tid] = 0;
    __syncthreads();
    for (int i = tid; i < cnt; i += 256) atomicAdd(&hist[(arr[i] >> 16) & 63], 1);
    __syncthreads();

    if (tid < 64) {
        int v = hist[tid];
        int inc = v;
        for (int o = 1; o < 64; o <<= 1) {
            int t = __shfl_up(inc, o, 64);
            if (tid >= o) inc += t;
        }
        bincur[tid] = inc - v;
        int node = b * 64 + tid;
        if (node < NNODES) rowptr[node] = base + inc - v;
    }
    if (b == 0 && tid == 0) rowptr[NNODES] = NTOT;
    __syncthreads();

    for (int i = tid; i < cnt; i += 256) {
        int r = arr[i];
        int pos = base + atomicAdd(&bincur[(r >> 16) & 63], 1);
        csr_src[pos] = r & 0xFFFF;
    }
}

// ---------------------------------------------------------------------------
// Kernel C: fused layer-1 softmax-aggregate (fp16 gather) + x1 = relu(.+b1)
// + GEMM2 row (W2 in LDS) + dots2 + h2 fp16 store. One wave per node.
// ---------------------------------------------------------------------------
__global__ __launch_bounds__(256) void agg1_gemm2_kernel(const int* __restrict__ rowptr,
                                                         const int* __restrict__ csr_src,
                                                         const _Float16* __restrict__ h1h,
                                                         const float* __restrict__ as1,
                                                         const float* __restrict__ ad1,
                                                         const float* __restrict__ b1,
                                                         const float* __restrict__ W2,
                                                         const float* __restrict__ a_src2,
                                                         const float* __restrict__ a_dst2,
                                                         _Float16* __restrict__ h2h,
                                                         float* __restrict__ as2,
                                                         float* __restrict__ ad2) {
    __shared__ float Wlds[H1 * H2];    // 32 KB
    __shared__ float xrow[4][H1];      // 2 KB
    int tid = threadIdx.x;
    {   // stage W2
        const float4* W4 = (const float4*)W2;
        float4* Wl4 = (float4*)Wlds;
        for (int idx = tid; idx < H1 * H2 / 4; idx += 256) Wl4[idx] = W4[idx];
    }
    int wv = tid >> 6, lane = tid & 63;
    int wid = blockIdx.x * 4 + wv;     // grid 2500*4 waves == NNODES exactly
    int beg = rowptr[wid], end = rowptr[wid + 1];
    float ad_d = ad1[wid];
    float z = 0.f, acc0 = 0.f, acc1 = 0.f;
    const half2v* h1p = (const half2v*)h1h;   // lane j -> features {2j,2j+1}

    for (int chunk = beg; chunk < end; chunk += 64) {
        int myj = chunk + lane;
        int cnt = end - chunk; if (cnt > 64) cnt = 64;
        int s_l = 0; float e_l = 0.f;
        if (myj < end) {
            s_l = csr_src[myj];
            float l = as1[s_l] + ad_d;
            l = (l > 0.f) ? l : 0.2f * l;
            e_l = __expf(l);
        }
        z += e_l;
        int cnt8 = (cnt + 7) & ~7;   // padded lanes carry e=0, s=0 -> harmless
        for (int t = 0; t < cnt8; t += 8) {
#pragma unroll
            for (int u = 0; u < 8; ++u) {
                int tt = __builtin_amdgcn_readfirstlane(t + u);
                int s = __builtin_amdgcn_readlane(s_l, tt);
                float e = __int_as_float(
                    __builtin_amdgcn_readlane(__float_as_int(e_l), tt));
                half2v hp = h1p[(size_t)s * 64 + lane];
                acc0 = fmaf(e, (float)hp.x, acc0);
                acc1 = fmaf(e, (float)hp.y, acc1);
            }
        }
    }
    for (int o = 32; o; o >>= 1) z += __shfl_xor(z, o, 64);
    float rz = 1.f / z;
    float2 bb = ((const float2*)b1)[lane];
    float v0 = fmaxf(acc0 * rz + bb.x, 0.f);
    float v1 = fmaxf(acc1 * rz + bb.y, 0.f);
    ((float2*)xrow[wv])[lane] = make_float2(v0, v1);   // same-wave write/read
    __syncthreads();   // W2 staging complete (xrow is per-wave, already safe)

    // GEMM2 row: this lane owns output column c = lane
    float hacc = 0.f;
    const float* xr = xrow[wv];
    for (int k = 0; k < H1; k += 4) {
        float4 xq = *(const float4*)&xr[k];   // wave-broadcast LDS read
        hacc = fmaf(xq.x, Wlds[(k + 0) * H2 + lane], hacc);
        hacc = fmaf(xq.y, Wlds[(k + 1) * H2 + lane], hacc);
        hacc = fmaf(xq.z, Wlds[(k + 2) * H2 + lane], hacc);
        hacc = fmaf(xq.w, Wlds[(k + 3) * H2 + lane], hacc);
    }
    // dots2 from registers
    float s1 = hacc * a_src2[lane];
    float s2 = hacc * a_dst2[lane];
    for (int o = 32; o; o >>= 1) {
        s1 += __shfl_xor(s1, o, 64);
        s2 += __shfl_xor(s2, o, 64);
    }
    if (lane == 0) { as2[wid] = s1; ad2[wid] = s2; }
    h2h[(size_t)wid * H2 + lane] = (_Float16)hacc;
}

// ---------------------------------------------------------------------------
// Kernel D: fused layer-2 softmax-aggregate (fp16 gather) + x2 = relu(.+b2)
// + projection (Wp in LDS) + bias -> out. One wave per node.
// ---------------------------------------------------------------------------
__global__ __launch_bounds__(256) void agg2_proj_kernel(const int* __restrict__ rowptr,
                                                        const int* __restrict__ csr_src,
                                                        const _Float16* __restrict__ h2h,
                                                        const float* __restrict__ as2,
                                                        const float* __restrict__ ad2,
                                                        const float* __restrict__ b2,
                                                        const float* __restrict__ Wp,
                                                        const float* __restrict__ bp,
                                                        float* __restrict__ out) {
    __shared__ float Wlds[H2 * EMB];   // 16 KB
    __shared__ float xrow[4][H2];
    int tid = threadIdx.x;
    {   // stage Wp
        const float4* W4 = (const float4*)Wp;
        float4* Wl4 = (float4*)Wlds;
        for (int idx = tid; idx < H2 * EMB / 4; idx += 256) Wl4[idx] = W4[idx];
    }
    int wv = tid >> 6, lane = tid & 63;
    int wid = blockIdx.x * 4 + wv;
    int beg = rowptr[wid], end = rowptr[wid + 1];
    float ad_d = ad2[wid];
    float z = 0.f, acc = 0.f;

    for (int chunk = beg; chunk < end; chunk += 64) {
        int myj = chunk + lane;
        int cnt = end - chunk; if (cnt > 64) cnt = 64;
        int s_l = 0; float e_l = 0.f;
        if (myj < end) {
            s_l = csr_src[myj];
            float l = as2[s_l] + ad_d;
            l = (l > 0.f) ? l : 0.2f * l;
            e_l = __expf(l);
        }
        z += e_l;
        int cnt8 = (cnt + 7) & ~7;
        for (int t = 0; t < cnt8; t += 8) {
#pragma unroll
            for (int u = 0; u < 8; ++u) {
                int tt = __builtin_amdgcn_readfirstlane(t + u);
                int s = __builtin_amdgcn_readlane(s_l, tt);
                float e = __int_as_float(
                    __builtin_amdgcn_readlane(__float_as_int(e_l), tt));
                acc = fmaf(e, (float)h2h[(size_t)s * H2 + lane], acc);
            }
        }
    }
    for (int o = 32; o; o >>= 1) z += __shfl_xor(z, o, 64);
    float x2v = fmaxf(acc * (1.f / z) + b2[lane], 0.f);
    xrow[wv][lane] = x2v;
    __syncthreads();   // Wp staging complete

    float oacc = 0.f;
    const float* xr = xrow[wv];
    for (int k = 0; k < H2; k += 4) {
        float4 xq = *(const float4*)&xr[k];
        oacc = fmaf(xq.x, Wlds[(k + 0) * EMB + lane], oacc);
        oacc = fmaf(xq.y, Wlds[(k + 1) * EMB + lane], oacc);
        oacc = fmaf(xq.z, Wlds[(k + 2) * EMB + lane], oacc);
        oacc = fmaf(xq.w, Wlds[(k + 3) * EMB + lane], oacc);
    }
    out[(size_t)wid * EMB + lane] = oacc + bp[lane];
}

// ---------------------------------------------------------------------------

extern "C" void kernel_launch(void* const* d_in, const int* in_sizes, int n_in,
                              void* d_out, int out_size, void* d_ws, size_t ws_size,
                              hipStream_t stream) {
    const float* x      = (const float*)d_in[0];
    const int*   ei     = (const int*)d_in[1];
    const float* W1     = (const float*)d_in[2];
    const float* a_src1 = (const float*)d_in[3];
    const float* a_dst1 = (const float*)d_in[4];
    const float* b1     = (const float*)d_in[5];
    const float* W2     = (const float*)d_in[6];
    const float* a_src2 = (const float*)d_in[7];
    const float* a_dst2 = (const float*)d_in[8];
    const float* b2     = (const float*)d_in[9];
    const float* Wp     = (const float*)d_in[10];
    const float* bp     = (const float*)d_in[11];
    float* out = (float*)d_out;

    char* ws = (char*)d_ws;
    size_t off = 0;
    auto alloc = [&](size_t bytes) {
        void* p = ws + off;
        off = (off + bytes + 255) & ~(size_t)255;
        return p;
    };
    int*      bucket_cursor = (int*)alloc(NBUCKET * 4);
    int*      bucket_arr    = (int*)alloc((size_t)NBUCKET * BCAP * 4);   // 5.2 MB
    int*      rowptr  = (int*)alloc((NNODES + 1) * 4);
    int*      csr_src = (int*)alloc((size_t)NTOT * 4);
    _Float16* h1h     = (_Float16*)alloc((size_t)NNODES * H1 * 2);       // 2.56 MB
    float*    as1     = (float*)alloc(NNODES * 4);
    float*    ad1     = (float*)alloc(NNODES * 4);
    _Float16* h2h     = (_Float16*)alloc((size_t)NNODES * H2 * 2);       // 1.28 MB
    float*    as2     = (float*)alloc(NNODES * 4);
    float*    ad2     = (float*)alloc(NNODES * 4);
    (void)ws_size;

    const int TB = 256;
    int wave_b = NNODES / 4;   // 2500 blocks, one wave per node

    hipMemsetAsync(bucket_cursor, 0, NBUCKET * 4, stream);

    // A: CSR bucket pass (blocks 0..158) || GEMM1+dots1 (blocks 159..471)
    csr_gemm1_kernel<<<NCHUNK + NTILE, TB, 0, stream>>>(
        ei, bucket_cursor, bucket_arr, x, W1, a_src1, a_dst1, h1h, as1, ad1);

    // B: rowptr + csr_src
    build_kernel<<<(NNODES + 63) / 64, TB, 0, stream>>>(bucket_cursor,
                                                        bucket_arr, rowptr, csr_src);

    // C: agg1 + gemm2 + dots2
    agg1_gemm2_kernel<<<wave_b, TB, 0, stream>>>(rowptr, csr_src, h1h, as1, ad1,
                                                 b1, W2, a_src2, a_dst2,
                                                 h2h, as2, ad2);

    // D: agg2 + projection
    agg2_proj_kernel<<<wave_b, TB, 0, stream>>>(rowptr, csr_src, h2h, as2, ad2,
                                                b2, Wp, bp, out);
}